// Round 5
// baseline (249.953 us; speedup 1.0000x reference)
//
#include <hip/hip_runtime.h>

#define NB 1024
#define LL 4096
#define PP 8192

__device__ __forceinline__ float2 cadd(float2 a, float2 b){ return make_float2(a.x+b.x, a.y+b.y); }
__device__ __forceinline__ float2 csub(float2 a, float2 b){ return make_float2(a.x-b.x, a.y-b.y); }
__device__ __forceinline__ float2 cmul(float2 a, float2 b){ return make_float2(a.x*b.x - a.y*b.y, a.x*b.y + a.y*b.x); }
__device__ __forceinline__ float2 cisf(float a){ float s, c; __sincosf(a, &s, &c); return make_float2(c, s); }

// W_32^j = (cos(pi j/16), -sin(pi j/16)), j in [0,16)
constexpr float W32R[16] = {
    1.0f, 0.9807852804f, 0.9238795325f, 0.8314696123f,
    0.7071067812f, 0.5555702330f, 0.3826834324f, 0.1950903220f,
    0.0f, -0.1950903220f, -0.3826834324f, -0.5555702330f,
    -0.7071067812f, -0.8314696123f, -0.9238795325f, -0.9807852804f };
constexpr float W32I[16] = {
    0.0f, -0.1950903220f, -0.3826834324f, -0.5555702330f,
    -0.7071067812f, -0.8314696123f, -0.9238795325f, -0.9807852804f,
    -1.0f, -0.9807852804f, -0.9238795325f, -0.8314696123f,
    -0.7071067812f, -0.5555702330f, -0.3826834324f, -0.1950903220f };

constexpr int REV5[32] = {0,16,8,24,4,20,12,28,2,18,10,26,6,22,14,30,
                          1,17,9,25,5,21,13,29,3,19,11,27,7,23,15,31};

// multiply by W_32^idx (forward) / conj (inverse); idx constant-folded in unrolled loops
__device__ __forceinline__ float2 twF(float2 b, int idx){
    if (idx == 0) return b;
    if (idx == 8) return make_float2(b.y, -b.x);
    return make_float2(b.x*W32R[idx] - b.y*W32I[idx], b.x*W32I[idx] + b.y*W32R[idx]);
}
__device__ __forceinline__ float2 twI(float2 b, int idx){
    if (idx == 0) return b;
    if (idx == 8) return make_float2(-b.y, b.x);
    return make_float2(b.x*W32R[idx] + b.y*W32I[idx], -b.x*W32I[idx] + b.y*W32R[idx]);
}

// DIF FFT-32: natural in, z[p] = X[REV5[p]] out. All twiddles compile-time.
__device__ __forceinline__ void fwd32(float2* z){
#pragma unroll
    for (int j = 0; j < 16; j++){ float2 a=z[j], b=z[j+16]; z[j]=cadd(a,b); z[j+16]=twF(csub(a,b), j); }
#pragma unroll
    for (int g = 0; g < 32; g += 16)
#pragma unroll
        for (int j = 0; j < 8; j++){ float2 a=z[g+j], b=z[g+j+8]; z[g+j]=cadd(a,b); z[g+j+8]=twF(csub(a,b), 2*j); }
#pragma unroll
    for (int g = 0; g < 32; g += 8)
#pragma unroll
        for (int j = 0; j < 4; j++){ float2 a=z[g+j], b=z[g+j+4]; z[g+j]=cadd(a,b); z[g+j+4]=twF(csub(a,b), 4*j); }
#pragma unroll
    for (int g = 0; g < 32; g += 4)
#pragma unroll
        for (int j = 0; j < 2; j++){ float2 a=z[g+j], b=z[g+j+2]; z[g+j]=cadd(a,b); z[g+j+2]=twF(csub(a,b), 8*j); }
#pragma unroll
    for (int g = 0; g < 32; g += 2){ float2 a=z[g], b=z[g+1]; z[g]=cadd(a,b); z[g+1]=csub(a,b); }
}
// DIT iFFT-32 (unscaled): z[p] = X[REV5[p]] in, natural time out.
__device__ __forceinline__ void inv32(float2* z){
#pragma unroll
    for (int g = 0; g < 32; g += 2){ float2 a=z[g], b=z[g+1]; z[g]=cadd(a,b); z[g+1]=csub(a,b); }
#pragma unroll
    for (int g = 0; g < 32; g += 4)
#pragma unroll
        for (int j = 0; j < 2; j++){ float2 b=twI(z[g+j+2], 8*j); float2 a=z[g+j]; z[g+j]=cadd(a,b); z[g+j+2]=csub(a,b); }
#pragma unroll
    for (int g = 0; g < 32; g += 8)
#pragma unroll
        for (int j = 0; j < 4; j++){ float2 b=twI(z[g+j+4], 4*j); float2 a=z[g+j]; z[g+j]=cadd(a,b); z[g+j+4]=csub(a,b); }
#pragma unroll
    for (int g = 0; g < 32; g += 16)
#pragma unroll
        for (int j = 0; j < 8; j++){ float2 b=twI(z[g+j+8], 2*j); float2 a=z[g+j]; z[g+j]=cadd(a,b); z[g+j+8]=csub(a,b); }
#pragma unroll
    for (int j = 0; j < 16; j++){ float2 b=twI(z[j+16], j); float2 a=z[j]; z[j]=cadd(a,b); z[j+16]=csub(a,b); }
}

// DIF FFT-8 on s[0..8): natural in, s[p] = X[rev3(p)] out (W_8^j = W_32^{4j})
__device__ __forceinline__ void fwd8(float2* s){
#pragma unroll
    for (int j = 0; j < 4; j++){ float2 a=s[j], b=s[j+4]; s[j]=cadd(a,b); s[j+4]=twF(csub(a,b), 4*j); }
#pragma unroll
    for (int g = 0; g < 8; g += 4)
#pragma unroll
        for (int j = 0; j < 2; j++){ float2 a=s[g+j], b=s[g+j+2]; s[g+j]=cadd(a,b); s[g+j+2]=twF(csub(a,b), 8*j); }
#pragma unroll
    for (int g = 0; g < 8; g += 2){ float2 a=s[g], b=s[g+1]; s[g]=cadd(a,b); s[g+1]=csub(a,b); }
}
__device__ __forceinline__ void inv8(float2* s){
#pragma unroll
    for (int g = 0; g < 8; g += 2){ float2 a=s[g], b=s[g+1]; s[g]=cadd(a,b); s[g+1]=csub(a,b); }
#pragma unroll
    for (int g = 0; g < 8; g += 4)
#pragma unroll
        for (int j = 0; j < 2; j++){ float2 b=twI(s[g+j+2], 8*j); float2 a=s[g+j]; s[g+j]=cadd(a,b); s[g+j+2]=csub(a,b); }
#pragma unroll
    for (int j = 0; j < 4; j++){ float2 b=twI(s[j+4], 4*j); float2 a=s[j]; s[j]=cadd(a,b); s[j+4]=csub(a,b); }
}

// Exchange-1 layout: logical (k1 in [0,32), n2 in [0,256)), n2 = m1*8+m2.
// phys bits: [b0-2:m2][b3:m1_0^k1_0][b4-7:m1>>1][b8:m1_0][b9-12:k1>>1] — bijective,
// residue mod 16 balanced for both writer (lanes n2) and reader (lanes m2+8*k1).
__device__ __forceinline__ int phys1(int k1, int n2){
    int m2 = n2 & 7, m1 = n2 >> 3;
    return m2 | ((((m1 ^ k1) & 1) << 3)) | ((m1 >> 1) << 4) | ((m1 & 1) << 8) | ((k1 >> 1) << 9);
}
// Exchange-2 layout: logical (k1, j1 in [0,32), m2 in [0,8)).
// phys bits: [b0-1:k1&3][b2:m2_0^j1_2][b3:m2_1^j1_3][b4:m2_2][b5-9:j1][b10-12:k1>>2]
__device__ __forceinline__ int phys2(int k1, int j1, int m2){
    return (k1 & 3)
         | ((((m2 ^ (j1 >> 2)) & 1) << 2))
         | (((((m2 >> 1) ^ (j1 >> 3)) & 1) << 3))
         | (((m2 >> 2) & 1) << 4)
         | (j1 << 5)
         | ((k1 >> 2) << 10);
}
// transposed 4096-slot layout for cs/bb: stride-16 thread access -> conflict-free
__device__ __forceinline__ int tslot(int i){ return ((i & 15) << 8) | (i >> 4); }
__device__ __forceinline__ int cslot(int i){ return (i >= LL) ? LL : tslot(i); }

__global__ __launch_bounds__(256) void k_all(
    const float* __restrict__ g_start, const float* __restrict__ g_end,
    const float* __restrict__ g_std,   const float* __restrict__ g_low,
    const float* __restrict__ g_up,    const int*   __restrict__ g_win,
    const float* __restrict__ g_scale, const float* __restrict__ g_noise,
    const float* __restrict__ g_omit,  const float* __restrict__ g_ppm,
    const float* __restrict__ g_ppmr,  float* __restrict__ g_out)
{
    __shared__ float2 buf[PP];          // 64 KB
    float* bf  = (float*)buf;
    float* rA  = bf + 4100;             // 4 floats
    float* rB  = bf + 4104;             // 4
    float* rC  = bf + 4108;             // 4
    float* shv = bf + 4112;             // 2

    const int n    = blockIdx.x;
    const int tid  = threadIdx.x;
    const int lane = tid & 63, wid = tid >> 6;
    const float st = g_start[n], en = g_end[n], sd = g_std[n];
    const float lo = g_low[n],   up = g_up[n];
    const int   w  = g_win[n];
    const float inv_nm1 = 1.0f / (float)(LL - 1);

    // ================= Phase A: walk + smooth + normalize =================
    float v[16];
    {
        const float4* p = (const float4*)(g_noise + (size_t)n * LL) + (size_t)tid * 4;
#pragma unroll
        for (int q = 0; q < 4; q++){ float4 t4 = p[q];
            v[4*q+0]=t4.x; v[4*q+1]=t4.y; v[4*q+2]=t4.z; v[4*q+3]=t4.w; }
    }
#pragma unroll
    for (int k = 0; k < 16; k++) v[k] = sd * (v[k] - 0.5f);

    // scan #1 (intra-thread + wave shfl + cross-wave)
    float run = 0.0f;
#pragma unroll
    for (int k = 0; k < 16; k++){ run += v[k]; v[k] = run; }
    float xs = run;
#pragma unroll
    for (int d = 1; d < 64; d <<= 1){ float y = __shfl_up(xs, d, 64); if (lane >= d) xs += y; }
    if (lane == 63) rA[wid] = xs;
    if (tid == 0)   shv[0] = v[0];
    __syncthreads();                                        // B1
    float a0 = rA[0], a1 = rA[1], a2 = rA[2], a3 = rA[3];
    float wexcl = (wid>0?a0:0.f) + (wid>1?a1:0.f) + (wid>2?a2:0.f);
    const float rT = a0 + a1 + a2 + a3;
    const float r0 = shv[0];
    float excl = wexcl + (xs - run);

    // detrend + min/max
    float del[16];
    float mx = -INFINITY, mn = INFINITY;
#pragma unroll
    for (int k = 0; k < 16; k++){
        int t = tid*16 + k;
        float d = (excl + v[k]) - (r0 + (rT - r0) * ((float)t * inv_nm1));
        del[k] = d; mx = fmaxf(mx, d); mn = fminf(mn, d);
    }
#pragma unroll
    for (int d = 1; d < 64; d <<= 1){ mx = fmaxf(mx, __shfl_xor(mx, d, 64)); mn = fminf(mn, __shfl_xor(mn, d, 64)); }
    if (lane == 0){ rB[wid] = mx; rC[wid] = mn; }
    __syncthreads();                                        // B2
    mx = fmaxf(fmaxf(rB[0],rB[1]), fmaxf(rB[2],rB[3]));
    mn = fminf(fminf(rC[0],rC[1]), fminf(rC[2],rC[3]));
    const float qs = fmaxf(1.0f, (mx - mn) / (up - lo));

    // squeeze + reflect + trend
    float wv[16];
#pragma unroll
    for (int k = 0; k < 16; k++){
        int t = tid*16 + k;
        float tr  = st + (en - st) * ((float)t * inv_nm1);
        float ub  = up - tr, lb2 = lo - tr;
        float d = del[k] / qs;
        float over = d - ub;   d = (over  >= 0.0f) ? (ub - over)  : d;
        float under = lb2 - d; d = (under >= 0.0f) ? (lb2 + under) : d;
        wv[k] = tr + d;
    }

    // scan #2 -> exclusive cumsum cs[0..LL] (transposed layout)
    run = 0.0f;
#pragma unroll
    for (int k = 0; k < 16; k++){ float x = wv[k]; run += x; wv[k] = run; }
    xs = run;
#pragma unroll
    for (int d = 1; d < 64; d <<= 1){ float y = __shfl_up(xs, d, 64); if (lane >= d) xs += y; }
    if (lane == 63) rA[wid] = xs;
    __syncthreads();                                        // B3
    a0 = rA[0]; a1 = rA[1]; a2 = rA[2]; a3 = rA[3];
    wexcl = (wid>0?a0:0.f) + (wid>1?a1:0.f) + (wid>2?a2:0.f);
    const float grand2 = a0 + a1 + a2 + a3;
    float excl2 = wexcl + (xs - run);
#pragma unroll
    for (int k = 0; k < 16; k++){
        int t = tid*16 + k;
        bf[tslot(t)] = excl2 + ((k == 0) ? 0.0f : wv[k-1]);
    }
    if (tid == 0) bf[LL] = grand2;                          // cs[4096] lives at slot 4096
    __syncthreads();                                        // B4

    // box smooth
    const int w2 = w / 2;
    const float invw = 1.0f / (float)w;
    float bvals[16];
#pragma unroll
    for (int k = 0; k < 16; k++){
        int t  = tid*16 + k;
        int li = t - w2; int hi = li + w;
        li = (li < 0) ? 0 : li;  hi = (hi > LL) ? LL : hi;
        bvals[k] = (bf[cslot(hi)] - bf[cslot(li)]) * invw;
    }
    if (tid == 0)   shv[0] = bvals[0];
    if (tid == 255) shv[1] = bvals[15];
    __syncthreads();                                        // B5
    const float b0 = shv[0], bL = shv[1];
    float am = 0.0f;
#pragma unroll
    for (int k = 0; k < 16; k++){
        int t = tid*16 + k;
        bvals[k] -= b0 + (bL - b0) * ((float)t * inv_nm1);
        am = fmaxf(am, fabsf(bvals[k]));
    }
#pragma unroll
    for (int d = 1; d < 64; d <<= 1) am = fmaxf(am, __shfl_xor(am, d, 64));
    if (lane == 0) rB[wid] = am;
    __syncthreads();                                        // B6
    float denom = fmaxf(fmaxf(rB[0],rB[1]), fmaxf(rB[2],rB[3]));
    denom = (denom == 0.0f) ? 1.0f : denom;
    const float fac = g_omit[n] * g_scale[n] / denom;

    // bb row (transposed layout, overwrites cs region — cs reads done before B5/B6)
#pragma unroll
    for (int k = 0; k < 16; k++){
        int t = tid*16 + k;
        bf[tslot(t)] = bvals[k] * fac;
    }
    __syncthreads();                                        // B7

    // ================= interp -> registers z[n1] = x[n1*256 + tid] ==========
    const float xlo = g_ppmr[0], xhi = g_ppmr[1];
    const float posmul = (float)(LL - 1) / (xhi - xlo);
    float2 z[32];
#pragma unroll
    for (int m = 0; m < 32; m++){
        int j = tid + m * 256;
        float x = g_ppm[j];
        float re = 0.0f;
        if (x >= xlo && x <= xhi){
            float pos = (x - xlo) * posmul;
            int i = (int)floorf(pos);
            i = (i < 0) ? 0 : ((i > LL - 2) ? (LL - 2) : i);
            float fr = pos - (float)i;
            float s0 = bf[tslot(i)], s1 = bf[tslot(i+1)];
            re = s0 + (s1 - s0) * fr;
        }
        z[m] = make_float2(re, 0.0f);
    }
    __syncthreads();                                        // B8 (bb reads done)

    // ================= forward: P1 (FFT-32 over n1) + twiddle + EX-1 ========
    fwd32(z);
    {
        float2 stp = cisf(-6.283185307179586f * (float)tid / 8192.0f);
        float2 tw = make_float2(1.0f, 0.0f);
#pragma unroll
        for (int k1 = 0; k1 < 32; k1++){
            buf[phys1(k1, tid)] = cmul(z[REV5[k1]], tw);
            tw = cmul(tw, stp);
        }
    }
    __syncthreads();                                        // B9 (EX-1 visible)

    const int k1 = tid >> 3;          // [0,32)
    const int m2 = tid & 7;           // [0,8)   (P2/P2' role)
    const int j1g = tid & 7;          //         (P3 role)

    // P2: FFT-32 over m1, per (k1, m2)
#pragma unroll
    for (int m1 = 0; m1 < 32; m1++) z[m1] = buf[phys1(k1, m1*8 + m2)];
    __syncthreads();                                        // B10 (EX-1 reads done)
    fwd32(z);
    {
        float2 stp = cisf(-6.283185307179586f * (float)m2 / 256.0f);
        float2 tw = make_float2(1.0f, 0.0f);
#pragma unroll
        for (int j1 = 0; j1 < 32; j1++){
            buf[phys2(k1, j1, m2)] = cmul(z[REV5[j1]], tw);
            tw = cmul(tw, stp);
        }
    }
    __syncthreads();                                        // B11 (EX-2 visible)

    // P3: FFT-8 over m2 per (k1, j1); filter; iFFT-8; row twiddle; write back (same slots)
#pragma unroll
    for (int dj = 0; dj < 4; dj++)
#pragma unroll
        for (int q = 0; q < 8; q++) z[dj*8 + q] = buf[phys2(k1, j1g*4 + dj, q)];

    const float invP = 1.0f / 8192.0f;
#pragma unroll
    for (int dj = 0; dj < 4; dj++){
        float2* s = z + dj*8;
        fwd8(s);
        float2 keep0 = s[0], keep1 = s[1];
#pragma unroll
        for (int p = 0; p < 8; p++){
            float g = (p & 1) ? 0.0f : (2.0f * invP);
            s[p].x *= g; s[p].y *= g;
        }
        if (tid == 0 && dj == 0){   // k==0 (p=0) and k==4096 (p=1) get gain 1/P
            s[0] = make_float2(keep0.x * invP, keep0.y * invP);
            s[1] = make_float2(keep1.x * invP, keep1.y * invP);
        }
        inv8(s);
        int j1 = j1g*4 + dj;
        float2 stp = cisf(6.283185307179586f * (float)j1 / 256.0f);
        float2 tw = make_float2(1.0f, 0.0f);
#pragma unroll
        for (int q = 0; q < 8; q++){
            buf[phys2(k1, j1, q)] = cmul(s[q], tw);
            tw = cmul(tw, stp);
        }
    }
    __syncthreads();                                        // B12 (EX-2' visible)

    // P2': iFFT-32 over j1, per (k1, m2); level-1 conj twiddle; EX-1' write
#pragma unroll
    for (int p = 0; p < 32; p++) z[p] = buf[phys2(k1, REV5[p], m2)];
    __syncthreads();                                        // B13 (EX-2' reads done)
    inv32(z);
    {
        float2 tw  = cisf(6.283185307179586f * (float)(m2 * k1) / 8192.0f);
        float2 stp = cisf(6.283185307179586f * (float)k1 / 1024.0f);
#pragma unroll
        for (int m1 = 0; m1 < 32; m1++){
            buf[phys1(k1, m1*8 + m2)] = cmul(z[m1], tw);
            tw = cmul(tw, stp);
        }
    }
    __syncthreads();                                        // B14 (EX-1' visible)

    // P1': iFFT-32 over k1 -> a[n1*256 + tid]; write outputs
#pragma unroll
    for (int p = 0; p < 32; p++) z[p] = buf[phys1(REV5[p], tid)];
    inv32(z);

    const size_t base1 = (size_t)NB * 2 * PP + (size_t)n * 2 * PP;  // raw
    const size_t base0 = (size_t)n * 2 * PP;                         // flipped
#pragma unroll
    for (int n1 = 0; n1 < 32; n1++){
        int idx = n1 * 256 + tid;
        float2 a = z[n1];
        g_out[base1 + idx]                = a.x;
        g_out[base1 + PP + idx]           = a.y;
        g_out[base0 + (PP - 1 - idx)]     = a.x;
        g_out[base0 + 2 * PP - 1 - idx]   = a.y;
    }
}

extern "C" void kernel_launch(void* const* d_in, const int* in_sizes, int n_in,
                              void* d_out, int out_size, void* d_ws, size_t ws_size,
                              hipStream_t stream)
{
    const float* start = (const float*)d_in[0];
    const float* end_  = (const float*)d_in[1];
    const float* stdv  = (const float*)d_in[2];
    const float* lowb  = (const float*)d_in[3];
    const float* upb   = (const float*)d_in[4];
    const int*   win   = (const int*)d_in[5];
    const float* scl   = (const float*)d_in[6];
    const float* noise = (const float*)d_in[7];
    const float* omit  = (const float*)d_in[8];
    const float* ppm   = (const float*)d_in[9];
    const float* ppmr  = (const float*)d_in[10];
    float* out = (float*)d_out;

    hipLaunchKernelGGL(k_all, dim3(NB), dim3(256), 0, stream,
                       start, end_, stdv, lowb, upb, win, scl, noise, omit,
                       ppm, ppmr, out);
}